// Round 6
// baseline (138.295 us; speedup 1.0000x reference)
//
#include <hip/hip_runtime.h>
#include <cmath>

#define BB  4
#define VV  4096
#define KK  40
#define FIN 64

typedef float v2f __attribute__((ext_vector_type(2)));

// ---------------------------------------------------------------------------
// Kernel A: 4 rows per wave; x rows loaded once coalesced, elements broadcast
// via v_readlane. Round-5: optionally also computes X2 = x @ Wo[0:64] (the
// x-part of the output GEMV), reusing the same readlane broadcasts.
// ---------------------------------------------------------------------------
__global__ __launch_bounds__(256) void prep_kernel(
    const float* __restrict__ x, const float* __restrict__ Wf,
    const float* __restrict__ bf, const float* __restrict__ Ws,
    const float* __restrict__ bs, const float* __restrict__ Wo,
    float* __restrict__ coords, float* __restrict__ sq,
    float* __restrict__ feats, float* __restrict__ X2)
{
    int lane = threadIdx.x & 63;
    int wid  = threadIdx.x >> 6;
    int row0 = (blockIdx.x * 4 + wid) * 4;        // 4 rows per wave
    const float* xr = x + (size_t)row0 * FIN;

    // whole rows in registers, coalesced (4 x 256B loads per wave)
    float rx0 = xr[lane];
    float rx1 = xr[64  + lane];
    float rx2 = xr[128 + lane];
    float rx3 = xr[192 + lane];

    float a0 = 0.f, a1 = 0.f, a2 = 0.f, a3 = 0.f;
    float y0 = 0.f, y1 = 0.f, y2 = 0.f, y3 = 0.f;
    bool do_x2 = (X2 != nullptr);
    #pragma unroll
    for (int k = 0; k < FIN; ++k) {
        float wf = Wf[k * 64 + lane];              // one coalesced 256B row
        float s0 = __uint_as_float(
             __builtin_amdgcn_readlane(__float_as_uint(rx0), k));
        float s1 = __uint_as_float(
             __builtin_amdgcn_readlane(__float_as_uint(rx1), k));
        float s2 = __uint_as_float(
             __builtin_amdgcn_readlane(__float_as_uint(rx2), k));
        float s3 = __uint_as_float(
             __builtin_amdgcn_readlane(__float_as_uint(rx3), k));
        a0 = fmaf(s0, wf, a0);
        a1 = fmaf(s1, wf, a1);
        a2 = fmaf(s2, wf, a2);
        a3 = fmaf(s3, wf, a3);
        if (do_x2) {
            float wo = Wo[k * 64 + lane];          // rows 0..63 of Wo
            y0 = fmaf(s0, wo, y0);
            y1 = fmaf(s1, wo, y1);
            y2 = fmaf(s2, wo, y2);
            y3 = fmaf(s3, wo, y3);
        }
    }
    float bfl = bf[lane];
    feats[(size_t)(row0 + 0) * 64 + lane] = a0 + bfl;
    feats[(size_t)(row0 + 1) * 64 + lane] = a1 + bfl;
    feats[(size_t)(row0 + 2) * 64 + lane] = a2 + bfl;
    feats[(size_t)(row0 + 3) * 64 + lane] = a3 + bfl;
    if (do_x2) {
        X2[(size_t)(row0 + 0) * 64 + lane] = y0;
        X2[(size_t)(row0 + 1) * 64 + lane] = y1;
        X2[(size_t)(row0 + 2) * 64 + lane] = y2;
        X2[(size_t)(row0 + 3) * 64 + lane] = y3;
    }

    // coords + sq for the same 4 rows (verbatim proven version)
    int r  = lane >> 4;                            // 0..3 row
    int s  = (lane >> 2) & 3;                      // 0..3 coord dim
    int kc = lane & 3;                             // 0..3 k-chunk
    const float* xrr = x + (size_t)(row0 + r) * FIN + kc * 16;
    const float* wsr = Ws + kc * 16 * 4 + s;
    float c = 0.f;
    #pragma unroll
    for (int k = 0; k < 16; ++k)
        c = fmaf(xrr[k], wsr[k * 4], c);
    c += __shfl_xor(c, 1, 64);                     // reduce over kc
    c += __shfl_xor(c, 2, 64);
    float val = c + bs[s];
    if ((lane & 3) == 0) coords[(size_t)(row0 + r) * 4 + s] = val;
    float p = val * val;
    p += __shfl_xor(p, 4, 64);                     // reduce over s
    p += __shfl_xor(p, 8, 64);
    if ((lane & 15) == 0) sq[row0 + r] = p;
}

// ---------------------------------------------------------------------------
// Spill-proof helpers (no runtime-indexed locals).
// ---------------------------------------------------------------------------
__device__ __forceinline__ unsigned umed3(unsigned a, unsigned b, unsigned c)
{
    unsigned d;
    asm("v_med3_u32 %0, %1, %2, %3" : "=v"(d) : "v"(a), "v"(b), "v"(c));
    return d;
}

__device__ __forceinline__ unsigned bfi_key(unsigned maskv, unsigned d2b,
                                            unsigned u)
{
    unsigned d;
    asm("v_bfi_b32 %0, %1, %2, %3" : "=v"(d) : "v"(maskv), "v"(d2b), "v"(u));
    return d;
}

__device__ __forceinline__ int cnt_lt4(unsigned m0, unsigned m1,
                                       unsigned m2, unsigned m3,
                                       unsigned cand)
{
    return (int)__popcll(__ballot(m0 < cand))
         + (int)__popcll(__ballot(m1 < cand))
         + (int)__popcll(__ballot(m2 < cand))
         + (int)__popcll(__ballot(m3 < cand));
}

__device__ __forceinline__ unsigned select_thresh(unsigned m0, unsigned m1,
                                                  unsigned m2, unsigned m3)
{
    unsigned M = 0u;
    #pragma unroll
    for (int bit = 30; bit >= 12; --bit) {
        unsigned cand = M | (1u << bit);
        if (cnt_lt4(m0, m1, m2, m3, cand) <= 39) M = cand;
    }
    unsigned Msel = M | 0xFFFu;
    if (cnt_lt4(m0, m1, m2, m3, M + 4096u) != 40) {
        #pragma unroll
        for (int bit = 11; bit >= 0; --bit) {
            unsigned cand = M | (1u << bit);
            if (cnt_lt4(m0, m1, m2, m3, cand) <= 39) M = cand;
        }
        Msel = M;
    }
    return Msel;
}

__device__ __forceinline__ void compact4(unsigned m0, unsigned m1,
                                         unsigned m2, unsigned m3,
                                         unsigned Msel, uint2* dst)
{
    unsigned mn = m0;
    #pragma unroll
    for (int off = 32; off >= 1; off >>= 1) {
        unsigned o = __shfl_xor(mn, off, 64);
        mn = o < mn ? o : mn;
    }
    int base = 0;
    unsigned kk = m0;
    #pragma unroll
    for (int i = 0; i < 4; ++i) {
        bool pred = (kk <= Msel) && (kk != mn);
        unsigned long long mask = __ballot(pred);
        unsigned pos = (unsigned)base +
            __builtin_amdgcn_mbcnt_hi((unsigned)(mask >> 32),
                __builtin_amdgcn_mbcnt_lo((unsigned)mask, 0u));
        if (pred) {
            float d2a = __uint_as_float(kk & 0xFFFFF000u);
            float w   = __expf(-10.f * d2a);
            dst[pos] = make_uint2((kk & 4095u) << 8, __float_as_uint(w));
        }
        base += (int)__popcll(mask);
        kk = (i == 0) ? m1 : (i == 1) ? m2 : m3;   // static rotation
    }
}

// ---------------------------------------------------------------------------
// Shared phase-1 body macro would obscure things; the two gravnet variants
// below differ only in the tail (GEMV) section.
//
// gravnet_x2: round-4 structure + (1) distance loop unroll 8 (deeper VMEM
// pipelining), (2) gather reads s_nb as uint4 (2 neighbors per ds_read),
// (3) GEMV 96->64 iters: x-part replaced by precomputed X2[q] (+bo init),
// s_upd shrinks to 1024B/wave.  LDS stays 8192 (s_mrg dominates).
// ---------------------------------------------------------------------------
__global__ __launch_bounds__(256, 8) void gravnet_x2(
    const float* __restrict__ coords, const float* __restrict__ sq,
    const float* __restrict__ feats, const float* __restrict__ Wo,
    const float* __restrict__ bo, const float* __restrict__ X2,
    float* __restrict__ out)
{
    int lane = threadIdx.x & 63;
    int w    = threadIdx.x >> 6;              // wave 0..3
    int quad = w >> 1;
    int half = w & 1;
    int bid  = (int)((blockIdx.x & 7) * 256 + (blockIdx.x >> 3));
    int qb   = bid * 8 + quad * 4;
    int b    = (bid * 8) >> 12;
    int v0   = qb & (VV - 1);

    __shared__ __align__(16) char smem[8192];
    uint4* s_mrg = (uint4*)smem;                       // [8][64] phase 1
    uint2* s_nb  = (uint2*)(smem + w * 2048);          // [2][KK] per wave
    float* s_upd = (float*)(smem + w * 2048);          // [256] per wave (aliases s_nb AFTER gather)

    const float4* cb  = (const float4*)(coords + (size_t)b * VV * 4);
    const float*  sqb = sq + (size_t)b * VV;

    float4 cq0 = cb[v0],     cq1 = cb[v0 + 1];
    float4 cq2 = cb[v0 + 2], cq3 = cb[v0 + 3];
    v2f nxA = (v2f){-2.f * cq0.x, -2.f * cq1.x};
    v2f nyA = (v2f){-2.f * cq0.y, -2.f * cq1.y};
    v2f nzA = (v2f){-2.f * cq0.z, -2.f * cq1.z};
    v2f nwA = (v2f){-2.f * cq0.w, -2.f * cq1.w};
    v2f hsA = (v2f){sqb[v0], sqb[v0 + 1]};
    v2f nxB = (v2f){-2.f * cq2.x, -2.f * cq3.x};
    v2f nyB = (v2f){-2.f * cq2.y, -2.f * cq3.y};
    v2f nzB = (v2f){-2.f * cq2.z, -2.f * cq3.z};
    v2f nwB = (v2f){-2.f * cq2.w, -2.f * cq3.w};
    v2f hsB = (v2f){sqb[v0 + 2], sqb[v0 + 3]};

    unsigned k00 = ~0u, k01 = ~0u, k02 = ~0u, k03 = ~0u;
    unsigned k10 = ~0u, k11 = ~0u, k12 = ~0u, k13 = ~0u;
    unsigned k20 = ~0u, k21 = ~0u, k22 = ~0u, k23 = ~0u;
    unsigned k30 = ~0u, k31 = ~0u, k32 = ~0u, k33 = ~0u;

    unsigned maskv = 0xFFFFF000u;

    int i0 = half * 32;
    #pragma unroll 8
    for (int i = i0; i < i0 + 32; ++i) {
        int u = i * 64 + lane;
        float4 cu = cb[u];
        float squ = sqb[u];
        v2f accA = hsA + (v2f){squ, squ};
        accA = __builtin_elementwise_fma(nxA, (v2f){cu.x, cu.x}, accA);
        accA = __builtin_elementwise_fma(nyA, (v2f){cu.y, cu.y}, accA);
        accA = __builtin_elementwise_fma(nzA, (v2f){cu.z, cu.z}, accA);
        accA = __builtin_elementwise_fma(nwA, (v2f){cu.w, cu.w}, accA);
        v2f accB = hsB + (v2f){squ, squ};
        accB = __builtin_elementwise_fma(nxB, (v2f){cu.x, cu.x}, accB);
        accB = __builtin_elementwise_fma(nyB, (v2f){cu.y, cu.y}, accB);
        accB = __builtin_elementwise_fma(nzB, (v2f){cu.z, cu.z}, accB);
        accB = __builtin_elementwise_fma(nwB, (v2f){cu.w, cu.w}, accB);

        {   // q0
            float d2 = fmaxf(accA.x, 0.f);
            unsigned k = bfi_key(maskv, __float_as_uint(d2), (unsigned)u);
            unsigned n1 = umed3(k00, k01, k);
            unsigned n2 = umed3(k01, k02, k);
            unsigned n3 = umed3(k02, k03, k);
            k00 = min(k00, k); k01 = n1; k02 = n2; k03 = n3;
        }
        {   // q1
            float d2 = fmaxf(accA.y, 0.f);
            unsigned k = bfi_key(maskv, __float_as_uint(d2), (unsigned)u);
            unsigned n1 = umed3(k10, k11, k);
            unsigned n2 = umed3(k11, k12, k);
            unsigned n3 = umed3(k12, k13, k);
            k10 = min(k10, k); k11 = n1; k12 = n2; k13 = n3;
        }
        {   // q2
            float d2 = fmaxf(accB.x, 0.f);
            unsigned k = bfi_key(maskv, __float_as_uint(d2), (unsigned)u);
            unsigned n1 = umed3(k20, k21, k);
            unsigned n2 = umed3(k21, k22, k);
            unsigned n3 = umed3(k22, k23, k);
            k20 = min(k20, k); k21 = n1; k22 = n2; k23 = n3;
        }
        {   // q3
            float d2 = fmaxf(accB.y, 0.f);
            unsigned k = bfi_key(maskv, __float_as_uint(d2), (unsigned)u);
            unsigned n1 = umed3(k30, k31, k);
            unsigned n2 = umed3(k31, k32, k);
            unsigned n3 = umed3(k32, k33, k);
            k30 = min(k30, k); k31 = n1; k32 = n2; k33 = n3;
        }
    }

    // --- publish ONLY the partner's 2 needed quads (8KB merge buffer)
    uint4 pub0 = half ? make_uint4(k00, k01, k02, k03)
                      : make_uint4(k20, k21, k22, k23);
    uint4 pub1 = half ? make_uint4(k10, k11, k12, k13)
                      : make_uint4(k30, k31, k32, k33);
    s_mrg[(w * 2 + 0) * 64 + lane] = pub0;
    s_mrg[(w * 2 + 1) * 64 + lane] = pub1;
    __syncthreads();

    int p   = w ^ 1;
    int lq0 = half * 2;
    uint4 pb0 = s_mrg[(p * 2 + 0) * 64 + lane];
    uint4 pb1 = s_mrg[(p * 2 + 1) * 64 + lane];
    unsigned oa0 = half ? k20 : k00, oa1 = half ? k21 : k01;
    unsigned oa2 = half ? k22 : k02, oa3 = half ? k23 : k03;
    unsigned ob0 = half ? k30 : k10, ob1 = half ? k31 : k11;
    unsigned ob2 = half ? k32 : k12, ob3 = half ? k33 : k13;
    __syncthreads();                           // before s_nb/s_upd reuse

    unsigned d0 = min(oa0, pb0.w), d1 = min(oa1, pb0.z);
    unsigned d2 = min(oa2, pb0.y), d3 = min(oa3, pb0.x);
    unsigned A0 = min(d0, d3), A3 = max(d0, d3);
    unsigned e0 = min(ob0, pb1.w), e1 = min(ob1, pb1.z);
    unsigned e2 = min(ob2, pb1.y), e3 = min(ob3, pb1.x);
    unsigned B0 = min(e0, e3), B3 = max(e0, e3);

    compact4(A0, d1, d2, A3, select_thresh(A0, d1, d2, A3), &s_nb[0]);
    compact4(B0, e1, e2, B3, select_thresh(B0, e1, e2, B3), &s_nb[KK]);

    // --- gather 39 neighbours x 2 queries: uint4 ds reads (2 nbrs/read)
    const float* fb  = feats + (size_t)b * VV * 64;
    const char*  fbl = (const char*)(fb + lane);
    const uint4* nb0 = (const uint4*)&s_nb[0];     // [19] pairs + tail
    const uint4* nb1 = (const uint4*)&s_nb[KK];    // s_nb[40]: 320B, 16B-aligned
    v2f vmax01 = (v2f){-INFINITY, -INFINITY};
    v2f vsum01 = (v2f){0.f, 0.f};
    #pragma unroll 4
    for (int jp = 0; jp < 19; ++jp) {
        uint4 a = nb0[jp];                     // {off_a0, w_a0, off_a1, w_a1}
        uint4 c = nb1[jp];
        float f0a = *(const float*)(fbl + a.x);
        float f1a = *(const float*)(fbl + c.x);
        float f0b = *(const float*)(fbl + a.z);
        float f1b = *(const float*)(fbl + c.z);
        v2f ga = (v2f){f0a, f1a} *
                 (v2f){__uint_as_float(a.y), __uint_as_float(c.y)};
        v2f gb = (v2f){f0b, f1b} *
                 (v2f){__uint_as_float(a.w), __uint_as_float(c.w)};
        vmax01 = __builtin_elementwise_max(vmax01,
                 __builtin_elementwise_max(ga, gb));
        vsum01 += ga + gb;
    }
    {   // tail j = 38
        uint2 n0 = s_nb[38];
        uint2 n1 = s_nb[KK + 38];
        float f0 = *(const float*)(fbl + n0.x);
        float f1 = *(const float*)(fbl + n1.x);
        v2f g01 = (v2f){f0, f1} *
                  (v2f){__uint_as_float(n0.y), __uint_as_float(n1.y)};
        vmax01 = __builtin_elementwise_max(vmax01, g01);
        vsum01 += g01;
    }

    // --- max/mean to per-wave LDS, interleaved {q0[j], q1[j]}
    int q0g = qb + lq0, q1g = qb + lq0 + 1;
    float* sb = s_upd;
    *(float2*)&sb[lane * 2] = make_float2(vmax01.x, vmax01.y);
    *(float2*)&sb[128 + lane * 2] =
        make_float2(vsum01.x * (1.0f / 39.0f), vsum01.y * (1.0f / 39.0f));

    // --- GEMV over Wo rows 64..191 only (x-part precomputed in X2)
    // row mapping: iter jj covers Wo rows 64+2jj, 65+2jj  (jj<32: max part,
    // jj>=32: mean part -- 128+2(jj-32) == 64+2jj, contiguous!)
    float bol = bo[lane];
    v2f acc01 = (v2f){bol + X2[(size_t)q0g * 64 + lane],
                      bol + X2[(size_t)q1g * 64 + lane]};
    const float* woB = Wo + 64 * 64;
    #pragma unroll 8
    for (int jj = 0; jj < 64; ++jj) {
        float wo0 = woB[(jj * 2 + 0) * 64 + lane];
        float wo1 = woB[(jj * 2 + 1) * 64 + lane];
        float4 up = *(const float4*)&sb[jj * 4];
        acc01 = __builtin_elementwise_fma((v2f){up.x, up.y},
                                          (v2f){wo0, wo0}, acc01);
        acc01 = __builtin_elementwise_fma((v2f){up.z, up.w},
                                          (v2f){wo1, wo1}, acc01);
    }
    float e0t = __expf(2.f * acc01.x);
    float e1t = __expf(2.f * acc01.y);
    out[(size_t)q0g * 64 + lane] = 1.f - __fdividef(2.f, e0t + 1.f);
    out[(size_t)q1g * 64 + lane] = 1.f - __fdividef(2.f, e1t + 1.f);
}

// ---------------------------------------------------------------------------
// Fallback gravnet (verbatim round-4, full 96-iter GEMV with x reload) --
// used only if the workspace is too small for X2.
// ---------------------------------------------------------------------------
__global__ __launch_bounds__(256, 8) void gravnet_kernel(
    const float* __restrict__ x, const float* __restrict__ coords,
    const float* __restrict__ sq, const float* __restrict__ feats,
    const float* __restrict__ Wo, const float* __restrict__ bo,
    float* __restrict__ out)
{
    int lane = threadIdx.x & 63;
    int w    = threadIdx.x >> 6;
    int quad = w >> 1;
    int half = w & 1;
    int bid  = (int)((blockIdx.x & 7) * 256 + (blockIdx.x >> 3));
    int qb   = bid * 8 + quad * 4;
    int b    = (bid * 8) >> 12;
    int v0   = qb & (VV - 1);

    __shared__ __align__(16) char smem[8192];
    uint4* s_mrg = (uint4*)smem;
    uint2* s_nb  = (uint2*)(smem + w * 2048);
    float* s_upd = (float*)(smem + w * 2048);

    const float4* cb  = (const float4*)(coords + (size_t)b * VV * 4);
    const float*  sqb = sq + (size_t)b * VV;

    float4 cq0 = cb[v0],     cq1 = cb[v0 + 1];
    float4 cq2 = cb[v0 + 2], cq3 = cb[v0 + 3];
    v2f nxA = (v2f){-2.f * cq0.x, -2.f * cq1.x};
    v2f nyA = (v2f){-2.f * cq0.y, -2.f * cq1.y};
    v2f nzA = (v2f){-2.f * cq0.z, -2.f * cq1.z};
    v2f nwA = (v2f){-2.f * cq0.w, -2.f * cq1.w};
    v2f hsA = (v2f){sqb[v0], sqb[v0 + 1]};
    v2f nxB = (v2f){-2.f * cq2.x, -2.f * cq3.x};
    v2f nyB = (v2f){-2.f * cq2.y, -2.f * cq3.y};
    v2f nzB = (v2f){-2.f * cq2.z, -2.f * cq3.z};
    v2f nwB = (v2f){-2.f * cq2.w, -2.f * cq3.w};
    v2f hsB = (v2f){sqb[v0 + 2], sqb[v0 + 3]};

    unsigned k00 = ~0u, k01 = ~0u, k02 = ~0u, k03 = ~0u;
    unsigned k10 = ~0u, k11 = ~0u, k12 = ~0u, k13 = ~0u;
    unsigned k20 = ~0u, k21 = ~0u, k22 = ~0u, k23 = ~0u;
    unsigned k30 = ~0u, k31 = ~0u, k32 = ~0u, k33 = ~0u;

    unsigned maskv = 0xFFFFF000u;

    int i0 = half * 32;
    #pragma unroll 4
    for (int i = i0; i < i0 + 32; ++i) {
        int u = i * 64 + lane;
        float4 cu = cb[u];
        float squ = sqb[u];
        v2f accA = hsA + (v2f){squ, squ};
        accA = __builtin_elementwise_fma(nxA, (v2f){cu.x, cu.x}, accA);
        accA = __builtin_elementwise_fma(nyA, (v2f){cu.y, cu.y}, accA);
        accA = __builtin_elementwise_fma(nzA, (v2f){cu.z, cu.z}, accA);
        accA = __builtin_elementwise_fma(nwA, (v2f){cu.w, cu.w}, accA);
        v2f accB = hsB + (v2f){squ, squ};
        accB = __builtin_elementwise_fma(nxB, (v2f){cu.x, cu.x}, accB);
        accB = __builtin_elementwise_fma(nyB, (v2f){cu.y, cu.y}, accB);
        accB = __builtin_elementwise_fma(nzB, (v2f){cu.z, cu.z}, accB);
        accB = __builtin_elementwise_fma(nwB, (v2f){cu.w, cu.w}, accB);

        {
            float d2 = fmaxf(accA.x, 0.f);
            unsigned k = bfi_key(maskv, __float_as_uint(d2), (unsigned)u);
            unsigned n1 = umed3(k00, k01, k);
            unsigned n2 = umed3(k01, k02, k);
            unsigned n3 = umed3(k02, k03, k);
            k00 = min(k00, k); k01 = n1; k02 = n2; k03 = n3;
        }
        {
            float d2 = fmaxf(accA.y, 0.f);
            unsigned k = bfi_key(maskv, __float_as_uint(d2), (unsigned)u);
            unsigned n1 = umed3(k10, k11, k);
            unsigned n2 = umed3(k11, k12, k);
            unsigned n3 = umed3(k12, k13, k);
            k10 = min(k10, k); k11 = n1; k12 = n2; k13 = n3;
        }
        {
            float d2 = fmaxf(accB.x, 0.f);
            unsigned k = bfi_key(maskv, __float_as_uint(d2), (unsigned)u);
            unsigned n1 = umed3(k20, k21, k);
            unsigned n2 = umed3(k21, k22, k);
            unsigned n3 = umed3(k22, k23, k);
            k20 = min(k20, k); k21 = n1; k22 = n2; k23 = n3;
        }
        {
            float d2 = fmaxf(accB.y, 0.f);
            unsigned k = bfi_key(maskv, __float_as_uint(d2), (unsigned)u);
            unsigned n1 = umed3(k30, k31, k);
            unsigned n2 = umed3(k31, k32, k);
            unsigned n3 = umed3(k32, k33, k);
            k30 = min(k30, k); k31 = n1; k32 = n2; k33 = n3;
        }
    }

    uint4 pub0 = half ? make_uint4(k00, k01, k02, k03)
                      : make_uint4(k20, k21, k22, k23);
    uint4 pub1 = half ? make_uint4(k10, k11, k12, k13)
                      : make_uint4(k30, k31, k32, k33);
    s_mrg[(w * 2 + 0) * 64 + lane] = pub0;
    s_mrg[(w * 2 + 1) * 64 + lane] = pub1;
    __syncthreads();

    int p   = w ^ 1;
    int lq0 = half * 2;
    uint4 pb0 = s_mrg[(p * 2 + 0) * 64 + lane];
    uint4 pb1 = s_mrg[(p * 2 + 1) * 64 + lane];
    unsigned oa0 = half ? k20 : k00, oa1 = half ? k21 : k01;
    unsigned oa2 = half ? k22 : k02, oa3 = half ? k23 : k03;
    unsigned ob0 = half ? k30 : k10, ob1 = half ? k31 : k11;
    unsigned ob2 = half ? k32 : k12, ob3 = half ? k33 : k13;
    __syncthreads();

    unsigned d0 = min(oa0, pb0.w), d1 = min(oa1, pb0.z);
    unsigned d2 = min(oa2, pb0.y), d3 = min(oa3, pb0.x);
    unsigned A0 = min(d0, d3), A3 = max(d0, d3);
    unsigned e0 = min(ob0, pb1.w), e1 = min(ob1, pb1.z);
    unsigned e2 = min(ob2, pb1.y), e3 = min(ob3, pb1.x);
    unsigned B0 = min(e0, e3), B3 = max(e0, e3);

    compact4(A0, d1, d2, A3, select_thresh(A0, d1, d2, A3), &s_nb[0]);
    compact4(B0, e1, e2, B3, select_thresh(B0, e1, e2, B3), &s_nb[KK]);

    const float* fb  = feats + (size_t)b * VV * 64;
    const char*  fbl = (const char*)(fb + lane);
    v2f vmax01 = (v2f){-INFINITY, -INFINITY};
    v2f vsum01 = (v2f){0.f, 0.f};
    #pragma unroll 6
    for (int j = 0; j < KK - 1; ++j) {
        uint2 n0 = s_nb[j];
        uint2 n1 = s_nb[KK + j];
        float f0 = *(const float*)(fbl + n0.x);
        float f1 = *(const float*)(fbl + n1.x);
        v2f g01 = (v2f){f0, f1} *
                  (v2f){__uint_as_float(n0.y), __uint_as_float(n1.y)};
        vmax01 = __builtin_elementwise_max(vmax01, g01);
        vsum01 += g01;
    }

    int q0g = qb + lq0, q1g = qb + lq0 + 1;
    float* sb = s_upd;
    *(float2*)&sb[lane * 2] =
        make_float2(x[(size_t)q0g * 64 + lane], x[(size_t)q1g * 64 + lane]);
    *(float2*)&sb[128 + lane * 2] = make_float2(vmax01.x, vmax01.y);
    *(float2*)&sb[256 + lane * 2] =
        make_float2(vsum01.x * (1.0f / 39.0f), vsum01.y * (1.0f / 39.0f));

    float bol = bo[lane];
    v2f acc01 = (v2f){bol, bol};
    #pragma unroll 8
    for (int jj = 0; jj < 96; ++jj) {
        float wo0 = Wo[(jj * 2 + 0) * 64 + lane];
        float wo1 = Wo[(jj * 2 + 1) * 64 + lane];
        float4 up = *(const float4*)&sb[jj * 4];
        acc01 = __builtin_elementwise_fma((v2f){up.x, up.y},
                                          (v2f){wo0, wo0}, acc01);
        acc01 = __builtin_elementwise_fma((v2f){up.z, up.w},
                                          (v2f){wo1, wo1}, acc01);
    }
    float e0t = __expf(2.f * acc01.x);
    float e1t = __expf(2.f * acc01.y);
    out[(size_t)q0g * 64 + lane] = 1.f - __fdividef(2.f, e0t + 1.f);
    out[(size_t)q1g * 64 + lane] = 1.f - __fdividef(2.f, e1t + 1.f);
}

// ---------------------------------------------------------------------------
extern "C" void kernel_launch(void* const* d_in, const int* in_sizes, int n_in,
                              void* d_out, int out_size, void* d_ws, size_t ws_size,
                              hipStream_t stream)
{
    (void)in_sizes; (void)n_in; (void)out_size;
    const float* x  = (const float*)d_in[0];
    const float* Wf = (const float*)d_in[1];
    const float* bf = (const float*)d_in[2];
    const float* Ws = (const float*)d_in[3];
    const float* bs = (const float*)d_in[4];
    const float* Wo = (const float*)d_in[5];
    const float* bo = (const float*)d_in[6];
    float* out = (float*)d_out;

    float* coords = (float*)d_ws;                     // B*V*4  floats (256 KB)
    float* sq     = coords + (size_t)BB * VV * 4;     // B*V    floats (64 KB)
    float* feats  = sq + (size_t)BB * VV;             // B*V*64 floats (4 MB)
    float* X2     = feats + (size_t)BB * VV * 64;     // B*V*64 floats (4 MB)

    size_t need = ((size_t)BB * VV * 4 + (size_t)BB * VV
                 + (size_t)BB * VV * 64 * 2) * sizeof(float);
    bool use_x2 = (ws_size >= need);

    prep_kernel<<<BB * VV / 16, 256, 0, stream>>>(
        x, Wf, bf, Ws, bs, Wo, coords, sq, feats, use_x2 ? X2 : nullptr);
    if (use_x2)
        gravnet_x2<<<BB * VV / 8, 256, 0, stream>>>(coords, sq, feats,
                                                    Wo, bo, X2, out);
    else
        gravnet_kernel<<<BB * VV / 8, 256, 0, stream>>>(x, coords, sq, feats,
                                                        Wo, bo, out);
}

// Round 7
// 126.916 us; speedup vs baseline: 1.0897x; 1.0897x over previous
//
#include <hip/hip_runtime.h>
#include <cmath>

#define BB  4
#define VV  4096
#define KK  40
#define FIN 64

typedef float v2f __attribute__((ext_vector_type(2)));

// ---------------------------------------------------------------------------
// Kernel A (round-2/4 proven): 4 rows per wave; x rows loaded once coalesced,
// elements broadcast via v_readlane (uniform k -> SGPR operand in FMA).
// (X2 fusion dropped: round-5 showed it net-zero time for 4x L2-miss traffic.)
// ---------------------------------------------------------------------------
__global__ __launch_bounds__(256) void prep_kernel(
    const float* __restrict__ x, const float* __restrict__ Wf,
    const float* __restrict__ bf, const float* __restrict__ Ws,
    const float* __restrict__ bs,
    float* __restrict__ coords, float* __restrict__ sq,
    float* __restrict__ feats)
{
    int lane = threadIdx.x & 63;
    int wid  = threadIdx.x >> 6;
    int row0 = (blockIdx.x * 4 + wid) * 4;        // 4 rows per wave
    const float* xr = x + (size_t)row0 * FIN;

    // whole rows in registers, coalesced (4 x 256B loads per wave)
    float rx0 = xr[lane];
    float rx1 = xr[64  + lane];
    float rx2 = xr[128 + lane];
    float rx3 = xr[192 + lane];

    float a0 = 0.f, a1 = 0.f, a2 = 0.f, a3 = 0.f;
    #pragma unroll
    for (int k = 0; k < FIN; ++k) {
        float wf = Wf[k * 64 + lane];              // one coalesced 256B row
        a0 = fmaf(__uint_as_float(
             __builtin_amdgcn_readlane(__float_as_uint(rx0), k)), wf, a0);
        a1 = fmaf(__uint_as_float(
             __builtin_amdgcn_readlane(__float_as_uint(rx1), k)), wf, a1);
        a2 = fmaf(__uint_as_float(
             __builtin_amdgcn_readlane(__float_as_uint(rx2), k)), wf, a2);
        a3 = fmaf(__uint_as_float(
             __builtin_amdgcn_readlane(__float_as_uint(rx3), k)), wf, a3);
    }
    float bfl = bf[lane];
    feats[(size_t)(row0 + 0) * 64 + lane] = a0 + bfl;
    feats[(size_t)(row0 + 1) * 64 + lane] = a1 + bfl;
    feats[(size_t)(row0 + 2) * 64 + lane] = a2 + bfl;
    feats[(size_t)(row0 + 3) * 64 + lane] = a3 + bfl;

    // coords + sq for the same 4 rows (verbatim proven version)
    int r  = lane >> 4;                            // 0..3 row
    int s  = (lane >> 2) & 3;                      // 0..3 coord dim
    int kc = lane & 3;                             // 0..3 k-chunk
    const float* xrr = x + (size_t)(row0 + r) * FIN + kc * 16;
    const float* wsr = Ws + kc * 16 * 4 + s;
    float c = 0.f;
    #pragma unroll
    for (int k = 0; k < 16; ++k)
        c = fmaf(xrr[k], wsr[k * 4], c);
    c += __shfl_xor(c, 1, 64);                     // reduce over kc
    c += __shfl_xor(c, 2, 64);
    float val = c + bs[s];
    if ((lane & 3) == 0) coords[(size_t)(row0 + r) * 4 + s] = val;
    float p = val * val;
    p += __shfl_xor(p, 4, 64);                     // reduce over s
    p += __shfl_xor(p, 8, 64);
    if ((lane & 15) == 0) sq[row0 + r] = p;
}

// ---------------------------------------------------------------------------
// Spill-proof helpers (no runtime-indexed locals).
// ---------------------------------------------------------------------------
__device__ __forceinline__ unsigned umed3(unsigned a, unsigned b, unsigned c)
{
    unsigned d;
    asm("v_med3_u32 %0, %1, %2, %3" : "=v"(d) : "v"(a), "v"(b), "v"(c));
    return d;
}

__device__ __forceinline__ unsigned bfi_key(unsigned maskv, unsigned d2b,
                                            unsigned u)
{
    unsigned d;
    asm("v_bfi_b32 %0, %1, %2, %3" : "=v"(d) : "v"(maskv), "v"(d2b), "v"(u));
    return d;
}

__device__ __forceinline__ int cnt_lt4(unsigned m0, unsigned m1,
                                       unsigned m2, unsigned m3,
                                       unsigned cand)
{
    return (int)__popcll(__ballot(m0 < cand))
         + (int)__popcll(__ballot(m1 < cand))
         + (int)__popcll(__ballot(m2 < cand))
         + (int)__popcll(__ballot(m3 < cand));
}

// rank-39 threshold: 19 value-bit radix steps; exact 12-step index-bit
// fallback only on a 20-bit boundary tie (rare, wave-uniform branch).
__device__ __forceinline__ unsigned select_thresh(unsigned m0, unsigned m1,
                                                  unsigned m2, unsigned m3)
{
    unsigned M = 0u;
    #pragma unroll
    for (int bit = 30; bit >= 12; --bit) {
        unsigned cand = M | (1u << bit);
        if (cnt_lt4(m0, m1, m2, m3, cand) <= 39) M = cand;
    }
    unsigned Msel = M | 0xFFFu;
    if (cnt_lt4(m0, m1, m2, m3, M + 4096u) != 40) {
        #pragma unroll
        for (int bit = 11; bit >= 0; --bit) {
            unsigned cand = M | (1u << bit);
            if (cnt_lt4(m0, m1, m2, m3, cand) <= 39) M = cand;
        }
        Msel = M;
    }
    return Msel;
}

// drop rank-0 (global min; m0 must hold the lane min) + compact the other 39
// as predecoded {byte_offset = u*256, weight = exp(-10*d2)} into LDS
__device__ __forceinline__ void compact4(unsigned m0, unsigned m1,
                                         unsigned m2, unsigned m3,
                                         unsigned Msel, uint2* dst)
{
    unsigned mn = m0;
    #pragma unroll
    for (int off = 32; off >= 1; off >>= 1) {
        unsigned o = __shfl_xor(mn, off, 64);
        mn = o < mn ? o : mn;
    }
    int base = 0;
    unsigned kk = m0;
    #pragma unroll
    for (int i = 0; i < 4; ++i) {
        bool pred = (kk <= Msel) && (kk != mn);
        unsigned long long mask = __ballot(pred);
        unsigned pos = (unsigned)base +
            __builtin_amdgcn_mbcnt_hi((unsigned)(mask >> 32),
                __builtin_amdgcn_mbcnt_lo((unsigned)mask, 0u));
        if (pred) {
            float d2a = __uint_as_float(kk & 0xFFFFF000u);
            float w   = __expf(-10.f * d2a);
            dst[pos] = make_uint2((kk & 4095u) << 8, __float_as_uint(w));
        }
        base += (int)__popcll(mask);
        kk = (i == 0) ? m1 : (i == 1) ? m2 : m3;   // static rotation
    }
}

// ---------------------------------------------------------------------------
// Kernel B (round-6): BARRIER-FREE waves. Evidence: rounds 3-5 showed op
// cuts (-15%, -10%) and traffic cuts (-65%) leave dur pinned at ~51us with
// VALUBusy*dur ~= 27us constant -> latency/residency-bound (only ~4.5
// blocks/CU resident; waves stall ~85% of their life on barriers + VMEM).
// Fix: each wave owns 2 queries and scans the FULL candidate set (64 iters
// x 2 chains -- same q-iters/query as the old split+merge), which deletes
// the bitonic merge, both __syncthreads, s_mrg, and all wave coupling.
// Blocks = 128 threads (2 independent waves, 4KB LDS), grid 4096 -> up to
// 16 WG/CU = 32 waves/CU can pack. Top-4-of-full-set is order-independent
// -> bit-identical output. Tail (radix/compact/uint4 gather/96-iter GEMV)
// verbatim from r4/r5 proven code.
// ---------------------------------------------------------------------------
__global__ __launch_bounds__(128, 8) void gravnet_kernel(
    const float* __restrict__ x, const float* __restrict__ coords,
    const float* __restrict__ sq, const float* __restrict__ feats,
    const float* __restrict__ Wo, const float* __restrict__ bo,
    float* __restrict__ out)
{
    int lane = threadIdx.x & 63;
    int w    = threadIdx.x >> 6;              // wave 0..1 (independent)
    // XCD swizzle: consecutive logical blocks land on the SAME XCD
    // (grid 4096, 4096 % 8 == 0 -> bijective; chunk = 512)
    int bid  = (int)((blockIdx.x & 7) * 512 + (blockIdx.x >> 3));
    int gw   = bid * 2 + w;                   // global wave id 0..8191
    int qb   = gw * 2;                        // this wave's first query
    int b    = qb >> 12;                      // batch
    int v0   = qb & (VV - 1);

    __shared__ __align__(16) char smem[4096];
    uint2* s_nb  = (uint2*)(smem + w * 2048);  // [2][KK] per wave
    float* s_upd = (float*)(smem + w * 2048);  // [384] per wave (aliases s_nb AFTER gather)

    const float4* cb  = (const float4*)(coords + (size_t)b * VV * 4);
    const float*  sqb = sq + (size_t)b * VV;

    // pair-packed query constants for the 2 queries (lane-uniform)
    float4 cq0 = cb[v0], cq1 = cb[v0 + 1];
    v2f nxA = (v2f){-2.f * cq0.x, -2.f * cq1.x};
    v2f nyA = (v2f){-2.f * cq0.y, -2.f * cq1.y};
    v2f nzA = (v2f){-2.f * cq0.z, -2.f * cq1.z};
    v2f nwA = (v2f){-2.f * cq0.w, -2.f * cq1.w};
    v2f hsA = (v2f){sqb[v0], sqb[v0 + 1]};

    // per-lane top-4 keys per query, individually named (spill-proof)
    unsigned k00 = ~0u, k01 = ~0u, k02 = ~0u, k03 = ~0u;
    unsigned k10 = ~0u, k11 = ~0u, k12 = ~0u, k13 = ~0u;

    unsigned maskv = 0xFFFFF000u;              // VGPR-resident bfi mask

    #pragma unroll 8
    for (int i = 0; i < 64; ++i) {             // FULL candidate scan
        int u = i * 64 + lane;
        float4 cu = cb[u];
        float squ = sqb[u];
        v2f accA = hsA + (v2f){squ, squ};
        accA = __builtin_elementwise_fma(nxA, (v2f){cu.x, cu.x}, accA);
        accA = __builtin_elementwise_fma(nyA, (v2f){cu.y, cu.y}, accA);
        accA = __builtin_elementwise_fma(nzA, (v2f){cu.z, cu.z}, accA);
        accA = __builtin_elementwise_fma(nwA, (v2f){cu.w, cu.w}, accA);

        {   // q0: min + 3x med3, depth 1
            float d2 = fmaxf(accA.x, 0.f);
            unsigned k = bfi_key(maskv, __float_as_uint(d2), (unsigned)u);
            unsigned n1 = umed3(k00, k01, k);
            unsigned n2 = umed3(k01, k02, k);
            unsigned n3 = umed3(k02, k03, k);
            k00 = min(k00, k); k01 = n1; k02 = n2; k03 = n3;
        }
        {   // q1
            float d2 = fmaxf(accA.y, 0.f);
            unsigned k = bfi_key(maskv, __float_as_uint(d2), (unsigned)u);
            unsigned n1 = umed3(k10, k11, k);
            unsigned n2 = umed3(k11, k12, k);
            unsigned n3 = umed3(k12, k13, k);
            k10 = min(k10, k); k11 = n1; k12 = n2; k13 = n3;
        }
    }

    // --- no merge, no barrier: k00/k10 already hold the lane-min of the
    // full set; radix select + compact directly into this wave's LDS region
    compact4(k00, k01, k02, k03,
             select_thresh(k00, k01, k02, k03), &s_nb[0]);
    compact4(k10, k11, k12, k13,
             select_thresh(k10, k11, k12, k13), &s_nb[KK]);
    // s_nb reads below are same-wave: no barrier needed

    // --- gather 39 neighbours x 2 queries: uint4 ds reads (2 nbrs/read)
    const float* fb  = feats + (size_t)b * VV * 64;
    const char*  fbl = (const char*)(fb + lane);
    const uint4* nb0 = (const uint4*)&s_nb[0];
    const uint4* nb1 = (const uint4*)&s_nb[KK];
    v2f vmax01 = (v2f){-INFINITY, -INFINITY};
    v2f vsum01 = (v2f){0.f, 0.f};
    #pragma unroll 4
    for (int jp = 0; jp < 19; ++jp) {
        uint4 a = nb0[jp];                     // {off_a0, w_a0, off_a1, w_a1}
        uint4 c = nb1[jp];
        float f0a = *(const float*)(fbl + a.x);
        float f1a = *(const float*)(fbl + c.x);
        float f0b = *(const float*)(fbl + a.z);
        float f1b = *(const float*)(fbl + c.z);
        v2f ga = (v2f){f0a, f1a} *
                 (v2f){__uint_as_float(a.y), __uint_as_float(c.y)};
        v2f gb = (v2f){f0b, f1b} *
                 (v2f){__uint_as_float(a.w), __uint_as_float(c.w)};
        vmax01 = __builtin_elementwise_max(vmax01,
                 __builtin_elementwise_max(ga, gb));
        vsum01 += ga + gb;
    }
    {   // tail j = 38
        uint2 n0 = s_nb[38];
        uint2 n1 = s_nb[KK + 38];
        float f0 = *(const float*)(fbl + n0.x);
        float f1 = *(const float*)(fbl + n1.x);
        v2f g01 = (v2f){f0, f1} *
                  (v2f){__uint_as_float(n0.y), __uint_as_float(n1.y)};
        vmax01 = __builtin_elementwise_max(vmax01, g01);
        vsum01 += g01;
    }

    // --- updated vectors to per-wave LDS, INTERLEAVED {q0[j], q1[j]} at j*2
    // (overwrites this wave's s_nb region -- gather above is complete,
    //  same-wave program order; no other wave touches this region)
    int q0g = qb, q1g = qb + 1;
    float* sb = s_upd;
    *(float2*)&sb[lane * 2] =
        make_float2(x[(size_t)q0g * 64 + lane], x[(size_t)q1g * 64 + lane]);
    *(float2*)&sb[128 + lane * 2] = make_float2(vmax01.x, vmax01.y);
    *(float2*)&sb[256 + lane * 2] =
        make_float2(vsum01.x * (1.0f / 39.0f), vsum01.y * (1.0f / 39.0f));

    // --- GEMV (192 x 64) x 2, packed: one b128 = 2 j's for both queries
    float bol = bo[lane];
    v2f acc01 = (v2f){bol, bol};
    #pragma unroll 8
    for (int jj = 0; jj < 96; ++jj) {
        float wo0 = Wo[(jj * 2 + 0) * 64 + lane];
        float wo1 = Wo[(jj * 2 + 1) * 64 + lane];
        float4 up = *(const float4*)&sb[jj * 4];
        acc01 = __builtin_elementwise_fma((v2f){up.x, up.y},
                                          (v2f){wo0, wo0}, acc01);
        acc01 = __builtin_elementwise_fma((v2f){up.z, up.w},
                                          (v2f){wo1, wo1}, acc01);
    }
    float e0t = __expf(2.f * acc01.x);         // tanh = 1 - 2/(e^2x+1)
    float e1t = __expf(2.f * acc01.y);
    out[(size_t)q0g * 64 + lane] = 1.f - __fdividef(2.f, e0t + 1.f);
    out[(size_t)q1g * 64 + lane] = 1.f - __fdividef(2.f, e1t + 1.f);
}

// ---------------------------------------------------------------------------
extern "C" void kernel_launch(void* const* d_in, const int* in_sizes, int n_in,
                              void* d_out, int out_size, void* d_ws, size_t ws_size,
                              hipStream_t stream)
{
    (void)in_sizes; (void)n_in; (void)out_size; (void)ws_size;
    const float* x  = (const float*)d_in[0];
    const float* Wf = (const float*)d_in[1];
    const float* bf = (const float*)d_in[2];
    const float* Ws = (const float*)d_in[3];
    const float* bs = (const float*)d_in[4];
    const float* Wo = (const float*)d_in[5];
    const float* bo = (const float*)d_in[6];
    float* out = (float*)d_out;

    float* coords = (float*)d_ws;                     // B*V*4  floats (256 KB)
    float* sq     = coords + (size_t)BB * VV * 4;     // B*V    floats (64 KB)
    float* feats  = sq + (size_t)BB * VV;             // B*V*64 floats (4 MB)

    prep_kernel<<<BB * VV / 16, 256, 0, stream>>>(x, Wf, bf, Ws, bs,
                                                  coords, sq, feats);
    gravnet_kernel<<<BB * VV / 4, 128, 0, stream>>>(x, coords, sq, feats,
                                                    Wo, bo, out);
}

// Round 8
// 118.833 us; speedup vs baseline: 1.1638x; 1.0680x over previous
//
#include <hip/hip_runtime.h>
#include <cmath>

#define BB  4
#define VV  4096
#define KK  40
#define FIN 64

typedef float v2f __attribute__((ext_vector_type(2)));

// ---------------------------------------------------------------------------
// Kernel A (round-2/4 proven): 4 rows per wave; x rows loaded once coalesced,
// elements broadcast via v_readlane (uniform k -> SGPR operand in FMA).
// ---------------------------------------------------------------------------
__global__ __launch_bounds__(256) void prep_kernel(
    const float* __restrict__ x, const float* __restrict__ Wf,
    const float* __restrict__ bf, const float* __restrict__ Ws,
    const float* __restrict__ bs,
    float* __restrict__ coords, float* __restrict__ sq,
    float* __restrict__ feats)
{
    int lane = threadIdx.x & 63;
    int wid  = threadIdx.x >> 6;
    int row0 = (blockIdx.x * 4 + wid) * 4;        // 4 rows per wave
    const float* xr = x + (size_t)row0 * FIN;

    // whole rows in registers, coalesced (4 x 256B loads per wave)
    float rx0 = xr[lane];
    float rx1 = xr[64  + lane];
    float rx2 = xr[128 + lane];
    float rx3 = xr[192 + lane];

    float a0 = 0.f, a1 = 0.f, a2 = 0.f, a3 = 0.f;
    #pragma unroll
    for (int k = 0; k < FIN; ++k) {
        float wf = Wf[k * 64 + lane];              // one coalesced 256B row
        a0 = fmaf(__uint_as_float(
             __builtin_amdgcn_readlane(__float_as_uint(rx0), k)), wf, a0);
        a1 = fmaf(__uint_as_float(
             __builtin_amdgcn_readlane(__float_as_uint(rx1), k)), wf, a1);
        a2 = fmaf(__uint_as_float(
             __builtin_amdgcn_readlane(__float_as_uint(rx2), k)), wf, a2);
        a3 = fmaf(__uint_as_float(
             __builtin_amdgcn_readlane(__float_as_uint(rx3), k)), wf, a3);
    }
    float bfl = bf[lane];
    feats[(size_t)(row0 + 0) * 64 + lane] = a0 + bfl;
    feats[(size_t)(row0 + 1) * 64 + lane] = a1 + bfl;
    feats[(size_t)(row0 + 2) * 64 + lane] = a2 + bfl;
    feats[(size_t)(row0 + 3) * 64 + lane] = a3 + bfl;

    // coords + sq for the same 4 rows (verbatim proven version)
    int r  = lane >> 4;                            // 0..3 row
    int s  = (lane >> 2) & 3;                      // 0..3 coord dim
    int kc = lane & 3;                             // 0..3 k-chunk
    const float* xrr = x + (size_t)(row0 + r) * FIN + kc * 16;
    const float* wsr = Ws + kc * 16 * 4 + s;
    float c = 0.f;
    #pragma unroll
    for (int k = 0; k < 16; ++k)
        c = fmaf(xrr[k], wsr[k * 4], c);
    c += __shfl_xor(c, 1, 64);                     // reduce over kc
    c += __shfl_xor(c, 2, 64);
    float val = c + bs[s];
    if ((lane & 3) == 0) coords[(size_t)(row0 + r) * 4 + s] = val;
    float p = val * val;
    p += __shfl_xor(p, 4, 64);                     // reduce over s
    p += __shfl_xor(p, 8, 64);
    if ((lane & 15) == 0) sq[row0 + r] = p;
}

// ---------------------------------------------------------------------------
// Spill-proof helpers (no runtime-indexed locals).
// ---------------------------------------------------------------------------
__device__ __forceinline__ unsigned umed3(unsigned a, unsigned b, unsigned c)
{
    unsigned d;
    asm("v_med3_u32 %0, %1, %2, %3" : "=v"(d) : "v"(a), "v"(b), "v"(c));
    return d;
}

__device__ __forceinline__ unsigned bfi_key(unsigned maskv, unsigned d2b,
                                            unsigned u)
{
    unsigned d;
    asm("v_bfi_b32 %0, %1, %2, %3" : "=v"(d) : "v"(maskv), "v"(d2b), "v"(u));
    return d;
}

__device__ __forceinline__ int cnt_lt4(unsigned m0, unsigned m1,
                                       unsigned m2, unsigned m3,
                                       unsigned cand)
{
    return (int)__popcll(__ballot(m0 < cand))
         + (int)__popcll(__ballot(m1 < cand))
         + (int)__popcll(__ballot(m2 < cand))
         + (int)__popcll(__ballot(m3 < cand));
}

// rank-39 threshold: 19 value-bit radix steps; exact 12-step index-bit
// fallback only on a 20-bit boundary tie (rare, wave-uniform branch).
__device__ __forceinline__ unsigned select_thresh(unsigned m0, unsigned m1,
                                                  unsigned m2, unsigned m3)
{
    unsigned M = 0u;
    #pragma unroll
    for (int bit = 30; bit >= 12; --bit) {
        unsigned cand = M | (1u << bit);
        if (cnt_lt4(m0, m1, m2, m3, cand) <= 39) M = cand;
    }
    unsigned Msel = M | 0xFFFu;
    if (cnt_lt4(m0, m1, m2, m3, M + 4096u) != 40) {
        #pragma unroll
        for (int bit = 11; bit >= 0; --bit) {
            unsigned cand = M | (1u << bit);
            if (cnt_lt4(m0, m1, m2, m3, cand) <= 39) M = cand;
        }
        Msel = M;
    }
    return Msel;
}

// drop rank-0 (global min; m0 must hold the lane min) + compact the other 39
// as predecoded {byte_offset = u*256, weight = exp(-10*d2)} into LDS
__device__ __forceinline__ void compact4(unsigned m0, unsigned m1,
                                         unsigned m2, unsigned m3,
                                         unsigned Msel, uint2* dst)
{
    unsigned mn = m0;
    #pragma unroll
    for (int off = 32; off >= 1; off >>= 1) {
        unsigned o = __shfl_xor(mn, off, 64);
        mn = o < mn ? o : mn;
    }
    int base = 0;
    unsigned kk = m0;
    #pragma unroll
    for (int i = 0; i < 4; ++i) {
        bool pred = (kk <= Msel) && (kk != mn);
        unsigned long long mask = __ballot(pred);
        unsigned pos = (unsigned)base +
            __builtin_amdgcn_mbcnt_hi((unsigned)(mask >> 32),
                __builtin_amdgcn_mbcnt_lo((unsigned)mask, 0u));
        if (pred) {
            float d2a = __uint_as_float(kk & 0xFFFFF000u);
            float w   = __expf(-10.f * d2a);
            dst[pos] = make_uint2((kk & 4095u) << 8, __float_as_uint(w));
        }
        base += (int)__popcll(mask);
        kk = (i == 0) ? m1 : (i == 1) ? m2 : m3;   // static rotation
    }
}

// ---------------------------------------------------------------------------
// Kernel B (round-7): 4 QUERIES PER WAVE, FULL SCAN, BARRIER-FREE.
// r6 lesson: independence alone regressed because per-query candidate load
// volume doubled (one cb[u] load served only 2 insert-chains). This round
// keeps r4's amortization (one load -> 4 chains: 335 MB L2 distance stream)
// AND r6's independence (no merge, no __syncthreads, no s_mrg), and halves
// Wo GEMV traffic (192 row-loads per 4 queries instead of per 2).
// Geometry: 1024 blocks x 256 thr (4 independent waves), 12KB LDS/block ->
// 4 blocks/CU -> ENTIRE grid resident in one occupancy round (no tail).
// Per-wave LDS 3072B: s_nb [4][KK] (1280B) aliased by s_upd [192][4] after
// the gather completes (same-wave program order only).
// ---------------------------------------------------------------------------
__global__ __launch_bounds__(256, 4) void gravnet_kernel(
    const float* __restrict__ x, const float* __restrict__ coords,
    const float* __restrict__ sq, const float* __restrict__ feats,
    const float* __restrict__ Wo, const float* __restrict__ bo,
    float* __restrict__ out)
{
    int lane = threadIdx.x & 63;
    int w    = threadIdx.x >> 6;              // wave 0..3 (independent)
    // XCD swizzle: consecutive logical blocks land on the SAME XCD
    // (grid 1024, 1024 % 8 == 0 -> bijective; chunk = 128)
    int bid  = (int)((blockIdx.x & 7) * 128 + (blockIdx.x >> 3));
    int gw   = bid * 4 + w;                   // global wave id 0..4095
    int qb   = gw * 4;                        // this wave's first query
    int b    = qb >> 12;                      // batch
    int v0   = qb & (VV - 1);

    __shared__ __align__(16) char smem[12288];
    uint2* s_nb  = (uint2*)(smem + w * 3072);  // [4][KK] per wave
    float* s_upd = (float*)(smem + w * 3072);  // [192][4] per wave (aliases s_nb AFTER gather)

    const float4* cb  = (const float4*)(coords + (size_t)b * VV * 4);
    const float*  sqb = sq + (size_t)b * VV;

    // pair-packed query constants for the 4 queries (lane-uniform)
    float4 cq0 = cb[v0],     cq1 = cb[v0 + 1];
    float4 cq2 = cb[v0 + 2], cq3 = cb[v0 + 3];
    v2f nxA = (v2f){-2.f * cq0.x, -2.f * cq1.x};
    v2f nyA = (v2f){-2.f * cq0.y, -2.f * cq1.y};
    v2f nzA = (v2f){-2.f * cq0.z, -2.f * cq1.z};
    v2f nwA = (v2f){-2.f * cq0.w, -2.f * cq1.w};
    v2f hsA = (v2f){sqb[v0], sqb[v0 + 1]};
    v2f nxB = (v2f){-2.f * cq2.x, -2.f * cq3.x};
    v2f nyB = (v2f){-2.f * cq2.y, -2.f * cq3.y};
    v2f nzB = (v2f){-2.f * cq2.z, -2.f * cq3.z};
    v2f nwB = (v2f){-2.f * cq2.w, -2.f * cq3.w};
    v2f hsB = (v2f){sqb[v0 + 2], sqb[v0 + 3]};

    // per-lane top-4 keys per query, individually named (spill-proof)
    unsigned k00 = ~0u, k01 = ~0u, k02 = ~0u, k03 = ~0u;
    unsigned k10 = ~0u, k11 = ~0u, k12 = ~0u, k13 = ~0u;
    unsigned k20 = ~0u, k21 = ~0u, k22 = ~0u, k23 = ~0u;
    unsigned k30 = ~0u, k31 = ~0u, k32 = ~0u, k33 = ~0u;

    unsigned maskv = 0xFFFFF000u;              // VGPR-resident bfi mask

    #pragma unroll 4
    for (int i = 0; i < 64; ++i) {             // FULL candidate scan
        int u = i * 64 + lane;
        float4 cu = cb[u];
        float squ = sqb[u];
        v2f accA = hsA + (v2f){squ, squ};
        accA = __builtin_elementwise_fma(nxA, (v2f){cu.x, cu.x}, accA);
        accA = __builtin_elementwise_fma(nyA, (v2f){cu.y, cu.y}, accA);
        accA = __builtin_elementwise_fma(nzA, (v2f){cu.z, cu.z}, accA);
        accA = __builtin_elementwise_fma(nwA, (v2f){cu.w, cu.w}, accA);
        v2f accB = hsB + (v2f){squ, squ};
        accB = __builtin_elementwise_fma(nxB, (v2f){cu.x, cu.x}, accB);
        accB = __builtin_elementwise_fma(nyB, (v2f){cu.y, cu.y}, accB);
        accB = __builtin_elementwise_fma(nzB, (v2f){cu.z, cu.z}, accB);
        accB = __builtin_elementwise_fma(nwB, (v2f){cu.w, cu.w}, accB);

        {   // q0: min + 3x med3, depth 1
            float d2 = fmaxf(accA.x, 0.f);
            unsigned k = bfi_key(maskv, __float_as_uint(d2), (unsigned)u);
            unsigned n1 = umed3(k00, k01, k);
            unsigned n2 = umed3(k01, k02, k);
            unsigned n3 = umed3(k02, k03, k);
            k00 = min(k00, k); k01 = n1; k02 = n2; k03 = n3;
        }
        {   // q1
            float d2 = fmaxf(accA.y, 0.f);
            unsigned k = bfi_key(maskv, __float_as_uint(d2), (unsigned)u);
            unsigned n1 = umed3(k10, k11, k);
            unsigned n2 = umed3(k11, k12, k);
            unsigned n3 = umed3(k12, k13, k);
            k10 = min(k10, k); k11 = n1; k12 = n2; k13 = n3;
        }
        {   // q2
            float d2 = fmaxf(accB.x, 0.f);
            unsigned k = bfi_key(maskv, __float_as_uint(d2), (unsigned)u);
            unsigned n1 = umed3(k20, k21, k);
            unsigned n2 = umed3(k21, k22, k);
            unsigned n3 = umed3(k22, k23, k);
            k20 = min(k20, k); k21 = n1; k22 = n2; k23 = n3;
        }
        {   // q3
            float d2 = fmaxf(accB.y, 0.f);
            unsigned k = bfi_key(maskv, __float_as_uint(d2), (unsigned)u);
            unsigned n1 = umed3(k30, k31, k);
            unsigned n2 = umed3(k31, k32, k);
            unsigned n3 = umed3(k32, k33, k);
            k30 = min(k30, k); k31 = n1; k32 = n2; k33 = n3;
        }
    }

    // --- no merge, no barrier: kq0 already holds the lane-min of the full
    // set; radix select + compact directly into this wave's LDS region
    compact4(k00, k01, k02, k03,
             select_thresh(k00, k01, k02, k03), &s_nb[0 * KK]);
    compact4(k10, k11, k12, k13,
             select_thresh(k10, k11, k12, k13), &s_nb[1 * KK]);
    compact4(k20, k21, k22, k23,
             select_thresh(k20, k21, k22, k23), &s_nb[2 * KK]);
    compact4(k30, k31, k32, k33,
             select_thresh(k30, k31, k32, k33), &s_nb[3 * KK]);
    // s_nb reads below are same-wave: no barrier needed

    // --- gather 39 neighbours x 4 queries: uint4 ds reads (2 nbrs/read)
    const float* fb  = feats + (size_t)b * VV * 64;
    const char*  fbl = (const char*)(fb + lane);
    const uint4* nb0 = (const uint4*)&s_nb[0 * KK];   // all 16B-aligned
    const uint4* nb1 = (const uint4*)&s_nb[1 * KK];   // (KK*8 = 320B)
    const uint4* nb2 = (const uint4*)&s_nb[2 * KK];
    const uint4* nb3 = (const uint4*)&s_nb[3 * KK];
    v2f vmax01 = (v2f){-INFINITY, -INFINITY};
    v2f vsum01 = (v2f){0.f, 0.f};
    v2f vmax23 = (v2f){-INFINITY, -INFINITY};
    v2f vsum23 = (v2f){0.f, 0.f};
    #pragma unroll 2
    for (int jp = 0; jp < 19; ++jp) {
        uint4 a = nb0[jp];                     // {off_j, w_j, off_j1, w_j1}
        uint4 c = nb1[jp];
        uint4 e = nb2[jp];
        uint4 g = nb3[jp];
        float f0a = *(const float*)(fbl + a.x);
        float f1a = *(const float*)(fbl + c.x);
        float f2a = *(const float*)(fbl + e.x);
        float f3a = *(const float*)(fbl + g.x);
        float f0b = *(const float*)(fbl + a.z);
        float f1b = *(const float*)(fbl + c.z);
        float f2b = *(const float*)(fbl + e.z);
        float f3b = *(const float*)(fbl + g.z);
        v2f ga01 = (v2f){f0a, f1a} *
                   (v2f){__uint_as_float(a.y), __uint_as_float(c.y)};
        v2f gb01 = (v2f){f0b, f1b} *
                   (v2f){__uint_as_float(a.w), __uint_as_float(c.w)};
        v2f ga23 = (v2f){f2a, f3a} *
                   (v2f){__uint_as_float(e.y), __uint_as_float(g.y)};
        v2f gb23 = (v2f){f2b, f3b} *
                   (v2f){__uint_as_float(e.w), __uint_as_float(g.w)};
        vmax01 = __builtin_elementwise_max(vmax01,
                 __builtin_elementwise_max(ga01, gb01));
        vsum01 += ga01 + gb01;
        vmax23 = __builtin_elementwise_max(vmax23,
                 __builtin_elementwise_max(ga23, gb23));
        vsum23 += ga23 + gb23;
    }
    {   // tail j = 38
        uint2 n0 = s_nb[0 * KK + 38];
        uint2 n1 = s_nb[1 * KK + 38];
        uint2 n2 = s_nb[2 * KK + 38];
        uint2 n3 = s_nb[3 * KK + 38];
        float f0 = *(const float*)(fbl + n0.x);
        float f1 = *(const float*)(fbl + n1.x);
        float f2 = *(const float*)(fbl + n2.x);
        float f3 = *(const float*)(fbl + n3.x);
        v2f g01 = (v2f){f0, f1} *
                  (v2f){__uint_as_float(n0.y), __uint_as_float(n1.y)};
        v2f g23 = (v2f){f2, f3} *
                  (v2f){__uint_as_float(n2.y), __uint_as_float(n3.y)};
        vmax01 = __builtin_elementwise_max(vmax01, g01);
        vsum01 += g01;
        vmax23 = __builtin_elementwise_max(vmax23, g23);
        vsum23 += g23;
    }

    // --- updated vectors to per-wave LDS, interleaved {q0,q1,q2,q3}[j] at
    // j*4 (overwrites this wave's s_nb region -- gather above is complete,
    // same-wave program order; no other wave touches this region)
    int q0g = qb, q1g = qb + 1, q2g = qb + 2, q3g = qb + 3;
    float* sb = s_upd;
    *(float4*)&sb[lane * 4] =
        make_float4(x[(size_t)q0g * 64 + lane], x[(size_t)q1g * 64 + lane],
                    x[(size_t)q2g * 64 + lane], x[(size_t)q3g * 64 + lane]);
    *(float4*)&sb[256 + lane * 4] =
        make_float4(vmax01.x, vmax01.y, vmax23.x, vmax23.y);
    *(float4*)&sb[512 + lane * 4] =
        make_float4(vsum01.x * (1.0f / 39.0f), vsum01.y * (1.0f / 39.0f),
                    vsum23.x * (1.0f / 39.0f), vsum23.y * (1.0f / 39.0f));

    // --- GEMV (192 x 64) x 4: one Wo row load + one ds_read_b128 feed all
    // 4 queries' component j  (Wo traffic per query HALVED vs rounds 3-6)
    float bol = bo[lane];
    v2f acc01 = (v2f){bol, bol};
    v2f acc23 = (v2f){bol, bol};
    #pragma unroll 8
    for (int j = 0; j < 192; ++j) {
        float wo = Wo[j * 64 + lane];
        float4 up = *(const float4*)&sb[j * 4];   // {u0[j],u1[j],u2[j],u3[j]}
        acc01 = __builtin_elementwise_fma((v2f){up.x, up.y},
                                          (v2f){wo, wo}, acc01);
        acc23 = __builtin_elementwise_fma((v2f){up.z, up.w},
                                          (v2f){wo, wo}, acc23);
    }
    float e0t = __expf(2.f * acc01.x);         // tanh = 1 - 2/(e^2x+1)
    float e1t = __expf(2.f * acc01.y);
    float e2t = __expf(2.f * acc23.x);
    float e3t = __expf(2.f * acc23.y);
    out[(size_t)q0g * 64 + lane] = 1.f - __fdividef(2.f, e0t + 1.f);
    out[(size_t)q1g * 64 + lane] = 1.f - __fdividef(2.f, e1t + 1.f);
    out[(size_t)q2g * 64 + lane] = 1.f - __fdividef(2.f, e2t + 1.f);
    out[(size_t)q3g * 64 + lane] = 1.f - __fdividef(2.f, e3t + 1.f);
}

// ---------------------------------------------------------------------------
extern "C" void kernel_launch(void* const* d_in, const int* in_sizes, int n_in,
                              void* d_out, int out_size, void* d_ws, size_t ws_size,
                              hipStream_t stream)
{
    (void)in_sizes; (void)n_in; (void)out_size; (void)ws_size;
    const float* x  = (const float*)d_in[0];
    const float* Wf = (const float*)d_in[1];
    const float* bf = (const float*)d_in[2];
    const float* Ws = (const float*)d_in[3];
    const float* bs = (const float*)d_in[4];
    const float* Wo = (const float*)d_in[5];
    const float* bo = (const float*)d_in[6];
    float* out = (float*)d_out;

    float* coords = (float*)d_ws;                     // B*V*4  floats (256 KB)
    float* sq     = coords + (size_t)BB * VV * 4;     // B*V    floats (64 KB)
    float* feats  = sq + (size_t)BB * VV;             // B*V*64 floats (4 MB)

    prep_kernel<<<BB * VV / 16, 256, 0, stream>>>(x, Wf, bf, Ws, bs,
                                                  coords, sq, feats);
    gravnet_kernel<<<BB * VV / 16, 256, 0, stream>>>(x, coords, sq, feats,
                                                     Wo, bo, out);
}

// Round 9
// 118.618 us; speedup vs baseline: 1.1659x; 1.0018x over previous
//
#include <hip/hip_runtime.h>
#include <cmath>

#define BB  4
#define VV  4096
#define KK  40
#define FIN 64

typedef float v2f __attribute__((ext_vector_type(2)));

// ---------------------------------------------------------------------------
// Kernel A (round-8): 2 rows per wave, grid 2048 blocks -> 8 blocks/CU =
// 32 waves/CU in ONE residency round (prep was 4 blocks/CU -- same
// residency disease as gravnet). x rows loaded once coalesced, elements
// broadcast via v_readlane (uniform k -> SGPR operand in FMA).
// ---------------------------------------------------------------------------
__global__ __launch_bounds__(256, 8) void prep_kernel(
    const float* __restrict__ x, const float* __restrict__ Wf,
    const float* __restrict__ bf, const float* __restrict__ Ws,
    const float* __restrict__ bs,
    float* __restrict__ coords, float* __restrict__ sq,
    float* __restrict__ feats)
{
    int lane = threadIdx.x & 63;
    int wid  = threadIdx.x >> 6;
    int row0 = (blockIdx.x * 4 + wid) * 2;        // 2 rows per wave
    const float* xr = x + (size_t)row0 * FIN;

    // both rows in registers, coalesced (2 x 256B loads per wave)
    float rx0 = xr[lane];
    float rx1 = xr[64 + lane];

    float a0 = 0.f, a1 = 0.f;
    #pragma unroll
    for (int k = 0; k < FIN; ++k) {
        float wf = Wf[k * 64 + lane];              // one coalesced 256B row
        a0 = fmaf(__uint_as_float(
             __builtin_amdgcn_readlane(__float_as_uint(rx0), k)), wf, a0);
        a1 = fmaf(__uint_as_float(
             __builtin_amdgcn_readlane(__float_as_uint(rx1), k)), wf, a1);
    }
    float bfl = bf[lane];
    feats[(size_t)(row0 + 0) * 64 + lane] = a0 + bfl;
    feats[(size_t)(row0 + 1) * 64 + lane] = a1 + bfl;

    // coords + sq for the same 2 rows: 32 lanes per row
    // lane = r*32 + s*8 + kc   (r: row, s: coord dim, kc: 8-chunk of k)
    int r  = lane >> 5;                            // 0..1 row
    int s  = (lane >> 3) & 3;                      // 0..3 coord dim
    int kc = lane & 7;                             // 0..7 k-chunk
    const float* xrr = x + (size_t)(row0 + r) * FIN + kc * 8;
    const float* wsr = Ws + kc * 8 * 4 + s;
    float c = 0.f;
    #pragma unroll
    for (int k = 0; k < 8; ++k)
        c = fmaf(xrr[k], wsr[k * 4], c);
    c += __shfl_xor(c, 1, 64);                     // reduce over kc (bits 0-2)
    c += __shfl_xor(c, 2, 64);
    c += __shfl_xor(c, 4, 64);
    float val = c + bs[s];
    if ((lane & 7) == 0) coords[(size_t)(row0 + r) * 4 + s] = val;
    float p = val * val;
    p += __shfl_xor(p, 8, 64);                     // reduce over s (bits 3-4)
    p += __shfl_xor(p, 16, 64);
    if ((lane & 31) == 0) sq[row0 + r] = p;
}

// ---------------------------------------------------------------------------
// Spill-proof helpers (no runtime-indexed locals).
// ---------------------------------------------------------------------------
__device__ __forceinline__ unsigned umed3(unsigned a, unsigned b, unsigned c)
{
    unsigned d;
    asm("v_med3_u32 %0, %1, %2, %3" : "=v"(d) : "v"(a), "v"(b), "v"(c));
    return d;
}

__device__ __forceinline__ unsigned bfi_key(unsigned maskv, unsigned d2b,
                                            unsigned u)
{
    unsigned d;
    asm("v_bfi_b32 %0, %1, %2, %3" : "=v"(d) : "v"(maskv), "v"(d2b), "v"(u));
    return d;
}

__device__ __forceinline__ int cnt_lt4(unsigned m0, unsigned m1,
                                       unsigned m2, unsigned m3,
                                       unsigned cand)
{
    return (int)__popcll(__ballot(m0 < cand))
         + (int)__popcll(__ballot(m1 < cand))
         + (int)__popcll(__ballot(m2 < cand))
         + (int)__popcll(__ballot(m3 < cand));
}

// QUAD rank-39 threshold: the 4 queries' 19 serial radix steps are
// INTERLEAVED in one loop -> 4x ILP on the cmp->popc->cselect hazard chain
// that round-7 ran as 4 sequential calls. Exact same per-query math.
__device__ __forceinline__ void select_thresh4(
    unsigned m00, unsigned m01, unsigned m02, unsigned m03,
    unsigned m10, unsigned m11, unsigned m12, unsigned m13,
    unsigned m20, unsigned m21, unsigned m22, unsigned m23,
    unsigned m30, unsigned m31, unsigned m32, unsigned m33,
    unsigned& Ms0, unsigned& Ms1, unsigned& Ms2, unsigned& Ms3)
{
    unsigned M0 = 0u, M1 = 0u, M2 = 0u, M3 = 0u;
    #pragma unroll
    for (int bit = 30; bit >= 12; --bit) {
        unsigned b = 1u << bit;
        unsigned c0 = M0 | b, c1 = M1 | b, c2 = M2 | b, c3 = M3 | b;
        int n0 = cnt_lt4(m00, m01, m02, m03, c0);
        int n1 = cnt_lt4(m10, m11, m12, m13, c1);
        int n2 = cnt_lt4(m20, m21, m22, m23, c2);
        int n3 = cnt_lt4(m30, m31, m32, m33, c3);
        if (n0 <= 39) M0 = c0;
        if (n1 <= 39) M1 = c1;
        if (n2 <= 39) M2 = c2;
        if (n3 <= 39) M3 = c3;
    }
    Ms0 = M0 | 0xFFFu; Ms1 = M1 | 0xFFFu;
    Ms2 = M2 | 0xFFFu; Ms3 = M3 | 0xFFFu;
    // exact index-bit fallback, per query (rare, wave-uniform branch)
    if (cnt_lt4(m00, m01, m02, m03, M0 + 4096u) != 40) {
        #pragma unroll
        for (int bit = 11; bit >= 0; --bit) {
            unsigned cand = M0 | (1u << bit);
            if (cnt_lt4(m00, m01, m02, m03, cand) <= 39) M0 = cand;
        }
        Ms0 = M0;
    }
    if (cnt_lt4(m10, m11, m12, m13, M1 + 4096u) != 40) {
        #pragma unroll
        for (int bit = 11; bit >= 0; --bit) {
            unsigned cand = M1 | (1u << bit);
            if (cnt_lt4(m10, m11, m12, m13, cand) <= 39) M1 = cand;
        }
        Ms1 = M1;
    }
    if (cnt_lt4(m20, m21, m22, m23, M2 + 4096u) != 40) {
        #pragma unroll
        for (int bit = 11; bit >= 0; --bit) {
            unsigned cand = M2 | (1u << bit);
            if (cnt_lt4(m20, m21, m22, m23, cand) <= 39) M2 = cand;
        }
        Ms2 = M2;
    }
    if (cnt_lt4(m30, m31, m32, m33, M3 + 4096u) != 40) {
        #pragma unroll
        for (int bit = 11; bit >= 0; --bit) {
            unsigned cand = M3 | (1u << bit);
            if (cnt_lt4(m30, m31, m32, m33, cand) <= 39) M3 = cand;
        }
        Ms3 = M3;
    }
}

// drop rank-0 (mn = precomputed global min; must equal min over m0..m3 of
// the wave) + compact the other 39 as predecoded {byte_offset = u*256,
// weight = exp(-10*d2)} into LDS.  (min-reduce hoisted out in round-8 so
// the 4 queries' reduce chains interleave at the call site.)
__device__ __forceinline__ void compact4(unsigned m0, unsigned m1,
                                         unsigned m2, unsigned m3,
                                         unsigned Msel, unsigned mn,
                                         uint2* dst)
{
    int base = 0;
    unsigned kk = m0;
    #pragma unroll
    for (int i = 0; i < 4; ++i) {
        bool pred = (kk <= Msel) && (kk != mn);
        unsigned long long mask = __ballot(pred);
        unsigned pos = (unsigned)base +
            __builtin_amdgcn_mbcnt_hi((unsigned)(mask >> 32),
                __builtin_amdgcn_mbcnt_lo((unsigned)mask, 0u));
        if (pred) {
            float d2a = __uint_as_float(kk & 0xFFFFF000u);
            float w   = __expf(-10.f * d2a);
            dst[pos] = make_uint2((kk & 4095u) << 8, __float_as_uint(w));
        }
        base += (int)__popcll(mask);
        kk = (i == 0) ? m1 : (i == 1) ? m2 : m3;   // static rotation
    }
}

// ---------------------------------------------------------------------------
// Kernel B (round-8): r7 structure (4 queries/wave, full scan, barrier-free)
// + serial-latency cuts:
//   (a) quad-interleaved radix select (select_thresh4) -- 4x ILP on the
//       19-step serial chain r7 ran 4x sequentially;
//   (b) hoisted + interleaved 4-way shfl min-reduce (was inside compact4);
//   (c) gather loads in s[uniform-base]+voffset form: compact stores row
//       byte-offset, gather adds lane*4 once -> 1 VALU/load (was 2-3);
//       unroll 2 -> 4 for more loads in flight.
// ---------------------------------------------------------------------------
__global__ __launch_bounds__(256, 4) void gravnet_kernel(
    const float* __restrict__ x, const float* __restrict__ coords,
    const float* __restrict__ sq, const float* __restrict__ feats,
    const float* __restrict__ Wo, const float* __restrict__ bo,
    float* __restrict__ out)
{
    int lane = threadIdx.x & 63;
    int w    = threadIdx.x >> 6;              // wave 0..3 (independent)
    // XCD swizzle (grid 1024, 1024 % 8 == 0 -> bijective; chunk = 128)
    int bid  = (int)((blockIdx.x & 7) * 128 + (blockIdx.x >> 3));
    int gw   = bid * 4 + w;                   // global wave id 0..4095
    int qb   = gw * 4;                        // this wave's first query
    int b    = qb >> 12;                      // batch
    int v0   = qb & (VV - 1);

    __shared__ __align__(16) char smem[12288];
    uint2* s_nb  = (uint2*)(smem + w * 3072);  // [4][KK] per wave
    float* s_upd = (float*)(smem + w * 3072);  // [192][4] per wave (aliases s_nb AFTER gather)

    const float4* cb  = (const float4*)(coords + (size_t)b * VV * 4);
    const float*  sqb = sq + (size_t)b * VV;

    // pair-packed query constants for the 4 queries (lane-uniform)
    float4 cq0 = cb[v0],     cq1 = cb[v0 + 1];
    float4 cq2 = cb[v0 + 2], cq3 = cb[v0 + 3];
    v2f nxA = (v2f){-2.f * cq0.x, -2.f * cq1.x};
    v2f nyA = (v2f){-2.f * cq0.y, -2.f * cq1.y};
    v2f nzA = (v2f){-2.f * cq0.z, -2.f * cq1.z};
    v2f nwA = (v2f){-2.f * cq0.w, -2.f * cq1.w};
    v2f hsA = (v2f){sqb[v0], sqb[v0 + 1]};
    v2f nxB = (v2f){-2.f * cq2.x, -2.f * cq3.x};
    v2f nyB = (v2f){-2.f * cq2.y, -2.f * cq3.y};
    v2f nzB = (v2f){-2.f * cq2.z, -2.f * cq3.z};
    v2f nwB = (v2f){-2.f * cq2.w, -2.f * cq3.w};
    v2f hsB = (v2f){sqb[v0 + 2], sqb[v0 + 3]};

    // per-lane top-4 keys per query, individually named (spill-proof)
    unsigned k00 = ~0u, k01 = ~0u, k02 = ~0u, k03 = ~0u;
    unsigned k10 = ~0u, k11 = ~0u, k12 = ~0u, k13 = ~0u;
    unsigned k20 = ~0u, k21 = ~0u, k22 = ~0u, k23 = ~0u;
    unsigned k30 = ~0u, k31 = ~0u, k32 = ~0u, k33 = ~0u;

    unsigned maskv = 0xFFFFF000u;              // VGPR-resident bfi mask

    #pragma unroll 4
    for (int i = 0; i < 64; ++i) {             // FULL candidate scan
        int u = i * 64 + lane;
        float4 cu = cb[u];
        float squ = sqb[u];
        v2f accA = hsA + (v2f){squ, squ};
        accA = __builtin_elementwise_fma(nxA, (v2f){cu.x, cu.x}, accA);
        accA = __builtin_elementwise_fma(nyA, (v2f){cu.y, cu.y}, accA);
        accA = __builtin_elementwise_fma(nzA, (v2f){cu.z, cu.z}, accA);
        accA = __builtin_elementwise_fma(nwA, (v2f){cu.w, cu.w}, accA);
        v2f accB = hsB + (v2f){squ, squ};
        accB = __builtin_elementwise_fma(nxB, (v2f){cu.x, cu.x}, accB);
        accB = __builtin_elementwise_fma(nyB, (v2f){cu.y, cu.y}, accB);
        accB = __builtin_elementwise_fma(nzB, (v2f){cu.z, cu.z}, accB);
        accB = __builtin_elementwise_fma(nwB, (v2f){cu.w, cu.w}, accB);

        {   // q0: min + 3x med3, depth 1
            float d2 = fmaxf(accA.x, 0.f);
            unsigned k = bfi_key(maskv, __float_as_uint(d2), (unsigned)u);
            unsigned n1 = umed3(k00, k01, k);
            unsigned n2 = umed3(k01, k02, k);
            unsigned n3 = umed3(k02, k03, k);
            k00 = min(k00, k); k01 = n1; k02 = n2; k03 = n3;
        }
        {   // q1
            float d2 = fmaxf(accA.y, 0.f);
            unsigned k = bfi_key(maskv, __float_as_uint(d2), (unsigned)u);
            unsigned n1 = umed3(k10, k11, k);
            unsigned n2 = umed3(k11, k12, k);
            unsigned n3 = umed3(k12, k13, k);
            k10 = min(k10, k); k11 = n1; k12 = n2; k13 = n3;
        }
        {   // q2
            float d2 = fmaxf(accB.x, 0.f);
            unsigned k = bfi_key(maskv, __float_as_uint(d2), (unsigned)u);
            unsigned n1 = umed3(k20, k21, k);
            unsigned n2 = umed3(k21, k22, k);
            unsigned n3 = umed3(k22, k23, k);
            k20 = min(k20, k); k21 = n1; k22 = n2; k23 = n3;
        }
        {   // q3
            float d2 = fmaxf(accB.y, 0.f);
            unsigned k = bfi_key(maskv, __float_as_uint(d2), (unsigned)u);
            unsigned n1 = umed3(k30, k31, k);
            unsigned n2 = umed3(k31, k32, k);
            unsigned n3 = umed3(k32, k33, k);
            k30 = min(k30, k); k31 = n1; k32 = n2; k33 = n3;
        }
    }

    // --- interleaved 4-way global-min reduce (hoisted from compact4)
    unsigned mn0 = k00, mn1 = k10, mn2 = k20, mn3 = k30;
    #pragma unroll
    for (int off = 32; off >= 1; off >>= 1) {
        unsigned o0 = __shfl_xor(mn0, off, 64);
        unsigned o1 = __shfl_xor(mn1, off, 64);
        unsigned o2 = __shfl_xor(mn2, off, 64);
        unsigned o3 = __shfl_xor(mn3, off, 64);
        mn0 = min(mn0, o0); mn1 = min(mn1, o1);
        mn2 = min(mn2, o2); mn3 = min(mn3, o3);
    }

    // --- quad-interleaved radix select + compact (no barriers anywhere)
    unsigned Ms0, Ms1, Ms2, Ms3;
    select_thresh4(k00, k01, k02, k03, k10, k11, k12, k13,
                   k20, k21, k22, k23, k30, k31, k32, k33,
                   Ms0, Ms1, Ms2, Ms3);
    compact4(k00, k01, k02, k03, Ms0, mn0, &s_nb[0 * KK]);
    compact4(k10, k11, k12, k13, Ms1, mn1, &s_nb[1 * KK]);
    compact4(k20, k21, k22, k23, Ms2, mn2, &s_nb[2 * KK]);
    compact4(k30, k31, k32, k33, Ms3, mn3, &s_nb[3 * KK]);
    // s_nb reads below are same-wave: no barrier needed

    // --- gather 39 neighbours x 4 queries: uint4 ds reads (2 nbrs/read),
    // loads in s[uniform fb]+voffset form (offset = row_off + lane*4)
    const float* fb  = feats + (size_t)b * VV * 64;   // block-uniform base
    unsigned lane4 = (unsigned)lane << 2;
    const uint4* nb0 = (const uint4*)&s_nb[0 * KK];   // all 16B-aligned
    const uint4* nb1 = (const uint4*)&s_nb[1 * KK];   // (KK*8 = 320B)
    const uint4* nb2 = (const uint4*)&s_nb[2 * KK];
    const uint4* nb3 = (const uint4*)&s_nb[3 * KK];
    v2f vmax01 = (v2f){-INFINITY, -INFINITY};
    v2f vsum01 = (v2f){0.f, 0.f};
    v2f vmax23 = (v2f){-INFINITY, -INFINITY};
    v2f vsum23 = (v2f){0.f, 0.f};
    #pragma unroll 4
    for (int jp = 0; jp < 19; ++jp) {
        uint4 a = nb0[jp];                     // {off_j, w_j, off_j1, w_j1}
        uint4 c = nb1[jp];
        uint4 e = nb2[jp];
        uint4 g = nb3[jp];
        float f0a = *(const float*)((const char*)fb + (a.x + lane4));
        float f1a = *(const float*)((const char*)fb + (c.x + lane4));
        float f2a = *(const float*)((const char*)fb + (e.x + lane4));
        float f3a = *(const float*)((const char*)fb + (g.x + lane4));
        float f0b = *(const float*)((const char*)fb + (a.z + lane4));
        float f1b = *(const float*)((const char*)fb + (c.z + lane4));
        float f2b = *(const float*)((const char*)fb + (e.z + lane4));
        float f3b = *(const float*)((const char*)fb + (g.z + lane4));
        v2f ga01 = (v2f){f0a, f1a} *
                   (v2f){__uint_as_float(a.y), __uint_as_float(c.y)};
        v2f gb01 = (v2f){f0b, f1b} *
                   (v2f){__uint_as_float(a.w), __uint_as_float(c.w)};
        v2f ga23 = (v2f){f2a, f3a} *
                   (v2f){__uint_as_float(e.y), __uint_as_float(g.y)};
        v2f gb23 = (v2f){f2b, f3b} *
                   (v2f){__uint_as_float(e.w), __uint_as_float(g.w)};
        vmax01 = __builtin_elementwise_max(vmax01,
                 __builtin_elementwise_max(ga01, gb01));
        vsum01 += ga01 + gb01;
        vmax23 = __builtin_elementwise_max(vmax23,
                 __builtin_elementwise_max(ga23, gb23));
        vsum23 += ga23 + gb23;
    }
    {   // tail j = 38
        uint2 n0 = s_nb[0 * KK + 38];
        uint2 n1 = s_nb[1 * KK + 38];
        uint2 n2 = s_nb[2 * KK + 38];
        uint2 n3 = s_nb[3 * KK + 38];
        float f0 = *(const float*)((const char*)fb + (n0.x + lane4));
        float f1 = *(const float*)((const char*)fb + (n1.x + lane4));
        float f2 = *(const float*)((const char*)fb + (n2.x + lane4));
        float f3 = *(const float*)((const char*)fb + (n3.x + lane4));
        v2f g01 = (v2f){f0, f1} *
                  (v2f){__uint_as_float(n0.y), __uint_as_float(n1.y)};
        v2f g23 = (v2f){f2, f3} *
                  (v2f){__uint_as_float(n2.y), __uint_as_float(n3.y)};
        vmax01 = __builtin_elementwise_max(vmax01, g01);
        vsum01 += g01;
        vmax23 = __builtin_elementwise_max(vmax23, g23);
        vsum23 += g23;
    }

    // --- updated vectors to per-wave LDS, interleaved {q0,q1,q2,q3}[j] at
    // j*4 (overwrites this wave's s_nb region -- gather above is complete,
    // same-wave program order; no other wave touches this region)
    int q0g = qb, q1g = qb + 1, q2g = qb + 2, q3g = qb + 3;
    float* sb = s_upd;
    *(float4*)&sb[lane * 4] =
        make_float4(x[(size_t)q0g * 64 + lane], x[(size_t)q1g * 64 + lane],
                    x[(size_t)q2g * 64 + lane], x[(size_t)q3g * 64 + lane]);
    *(float4*)&sb[256 + lane * 4] =
        make_float4(vmax01.x, vmax01.y, vmax23.x, vmax23.y);
    *(float4*)&sb[512 + lane * 4] =
        make_float4(vsum01.x * (1.0f / 39.0f), vsum01.y * (1.0f / 39.0f),
                    vsum23.x * (1.0f / 39.0f), vsum23.y * (1.0f / 39.0f));

    // --- GEMV (192 x 64) x 4: one Wo row load + one ds_read_b128 feed all
    // 4 queries' component j
    float bol = bo[lane];
    v2f acc01 = (v2f){bol, bol};
    v2f acc23 = (v2f){bol, bol};
    #pragma unroll 8
    for (int j = 0; j < 192; ++j) {
        float wo = Wo[j * 64 + lane];
        float4 up = *(const float4*)&sb[j * 4];   // {u0[j],u1[j],u2[j],u3[j]}
        acc01 = __builtin_elementwise_fma((v2f){up.x, up.y},
                                          (v2f){wo, wo}, acc01);
        acc23 = __builtin_elementwise_fma((v2f){up.z, up.w},
                                          (v2f){wo, wo}, acc23);
    }
    float e0t = __expf(2.f * acc01.x);         // tanh = 1 - 2/(e^2x+1)
    float e1t = __expf(2.f * acc01.y);
    float e2t = __expf(2.f * acc23.x);
    float e3t = __expf(2.f * acc23.y);
    out[(size_t)q0g * 64 + lane] = 1.f - __fdividef(2.f, e0t + 1.f);
    out[(size_t)q1g * 64 + lane] = 1.f - __fdividef(2.f, e1t + 1.f);
    out[(size_t)q2g * 64 + lane] = 1.f - __fdividef(2.f, e2t + 1.f);
    out[(size_t)q3g * 64 + lane] = 1.f - __fdividef(2.f, e3t + 1.f);
}

// ---------------------------------------------------------------------------
extern "C" void kernel_launch(void* const* d_in, const int* in_sizes, int n_in,
                              void* d_out, int out_size, void* d_ws, size_t ws_size,
                              hipStream_t stream)
{
    (void)in_sizes; (void)n_in; (void)out_size; (void)ws_size;
    const float* x  = (const float*)d_in[0];
    const float* Wf = (const float*)d_in[1];
    const float* bf = (const float*)d_in[2];
    const float* Ws = (const float*)d_in[3];
    const float* bs = (const float*)d_in[4];
    const float* Wo = (const float*)d_in[5];
    const float* bo = (const float*)d_in[6];
    float* out = (float*)d_out;

    float* coords = (float*)d_ws;                     // B*V*4  floats (256 KB)
    float* sq     = coords + (size_t)BB * VV * 4;     // B*V    floats (64 KB)
    float* feats  = sq + (size_t)BB * VV;             // B*V*64 floats (4 MB)

    prep_kernel<<<BB * VV / 8, 256, 0, stream>>>(x, Wf, bf, Ws, bs,
                                                 coords, sq, feats);
    gravnet_kernel<<<BB * VV / 16, 256, 0, stream>>>(x, coords, sq, feats,
                                                     Wo, bo, out);
}